// Round 9
// baseline (207.854 us; speedup 1.0000x reference)
//
#include <hip/hip_runtime.h>
#include <cstdint>
#include <cstddef>

#define BB 32
#define NN 8400
#define NCC 80
#define MM 40
#define RM 16
#define TOPKK 10
#define CAP 2048      // max positives per (b,m); measured worst case ~450, 4.5x margin
#define SLOTP 41      // LDS stride for per-slot sigmoid tile; gcd(41,32)=1
#define AB 64         // anchors per k_mono block

// ---------- helpers ----------
__device__ __forceinline__ void anchor_xy(int n, float& ax, float& ay) {
    int s, x, y;
    if (n < 6400)      { s = 8;  y = n / 80;            x = n - y * 80; }
    else if (n < 8000) { int i = n - 6400; s = 16; y = i / 40; x = i - y * 40; }
    else               { int i = n - 8000; s = 32; y = i / 20; x = i - y * 20; }
    ax = ((float)x + 0.5f) * (float)s;
    ay = ((float)y + 0.5f) * (float)s;
}

// async global->LDS, 16B per lane, wave-uniform LDS base + lane*16 (HW rule m104)
__device__ __forceinline__ void gld16(const float* g, float* l) {
    __builtin_amdgcn_global_load_lds((const __attribute__((address_space(1))) void*)g,
                                     (__attribute__((address_space(3))) void*)l,
                                     16, 0, 0);
}

// ---------- K_mono: DFL + sigmoid/softplus + align; ps tile via global_load_lds ----------
// grid: (ceil(N/64), B), 256 threads.
// Structure: issue pd reg-loads + DMA the whole 64x80 ps tile to LDS FIRST; the
// first __syncthreads' mandatory vmcnt(0) drain pays ALL memory latency once.
// After it: DFL from regs, sigmoid/softplus from LDS, align from LDS — no global
// waits. global_load_lds holds no VGPRs, so the compiler cannot sink it (the
// mechanism that defeated R4/R6/R7 register prefetch).
__global__ __launch_bounds__(256, 4) void k_mono(const float* __restrict__ ps,
                                                 const float* __restrict__ pd,
                                                 const int*   __restrict__ gl,
                                                 const float* __restrict__ gb,
                                                 const float* __restrict__ w,
                                                 float* __restrict__ pbb,
                                                 float* __restrict__ maxm,
                                                 int*   __restrict__ cnts,
                                                 unsigned long long* __restrict__ lists,
                                                 float* __restrict__ accum,
                                                 int*   __restrict__ tgt) {
    __shared__ float4 raw4[AB * NCC / 4];   // 20 KB raw score tile (DMA target), 16B-aligned
    __shared__ float  sc[AB * SLOTP];       // sigmoid per (nloc, slot), 10.5 KB
    __shared__ float  boxf[AB * 4];         // pred boxes (t = a*4+side maps 1:1)
    __shared__ float  gtb[MM * 4];
    __shared__ int    glab[MM];
    __shared__ int    slotm[MM];
    __shared__ int    cmap[NCC];
    __shared__ float  cm[256];
    __shared__ float  redf[4];
    const int b  = blockIdx.y;
    const int n0 = blockIdx.x * AB;
    const int t  = threadIdx.x;

    // fused tgt init (replaces a 1 MB memset node)
    if (t < AB && n0 + t < NN) tgt[(size_t)b * NN + n0 + t] = 0x7F7F7F7F;

    // ---- issue pd register loads: 1 (anchor,side) per thread ----
    const int a    = t >> 2, side = t & 3;
    const int nA   = n0 + a;
    const int ncA  = min(nA, NN - 1);
    const float* p = pd + (((size_t)(b * NN + ncA)) * 4 + side) * RM;
    float4 xa0 = *(const float4*)(p);
    float4 xa1 = *(const float4*)(p + 4);
    float4 xa2 = *(const float4*)(p + 8);
    float4 xa3 = *(const float4*)(p + 12);

    // ---- issue ps tile DMA: 20 chunks of 1KB; wave wv issues chunks wv+4k ----
    {
        const int wv = t >> 6;
        #pragma unroll
        for (int k = 0; k < 5; k++) {
            int f = t + k * 256;                 // float4 index in [0,1280)
            int row = f / 20, c4 = f - row * 20; // 20 float4 per 80-float row
            int nc = min(n0 + row, NN - 1);
            const float* g = ps + ((size_t)(b * NN + nc)) * NCC + c4 * 4;
            gld16(g, (float*)(raw4 + (wv + 4 * k) * 64));
        }
    }
    __builtin_amdgcn_sched_barrier(0);          // pin: DMA issued before setup

    // ---- LDS setup (small loads overlap in-flight DMA) ----
    if (t < MM * 4)              gtb[t] = gb[b * MM * 4 + t];
    if (t >= 192 && t < 192+MM)  glab[t - 192] = gl[b * MM + (t - 192)];
    if (t >= 96 && t < 96+NCC)   cmap[t - 96] = 0x7FFFFFFF;
    asm volatile("" :: "v"(xa0.x), "v"(xa1.x), "v"(xa2.x), "v"(xa3.x)); // pin pd issue
    __syncthreads();   // vmcnt(0) drain: ALL memory latency paid here, once
    if (t < MM) atomicMin(&cmap[glab[t]], t);   // parallel label dedup
    __syncthreads();
    if (t < MM) slotm[t] = cmap[glab[t]];       // slot = representative m, in [0,MM)

    // ---- DFL softmax-dot -> one box component per thread (regs already loaded) ----
    {
        float x[RM];
        x[0]=xa0.x;  x[1]=xa0.y;  x[2]=xa0.z;  x[3]=xa0.w;
        x[4]=xa1.x;  x[5]=xa1.y;  x[6]=xa1.z;  x[7]=xa1.w;
        x[8]=xa2.x;  x[9]=xa2.y;  x[10]=xa2.z; x[11]=xa2.w;
        x[12]=xa3.x; x[13]=xa3.y; x[14]=xa3.z; x[15]=xa3.w;
        float mx = x[0];
        #pragma unroll
        for (int i = 1; i < RM; i++) mx = fmaxf(mx, x[i]);
        float s = 0.f, d = 0.f;
        #pragma unroll
        for (int i = 0; i < RM; i++) {
            float e = __builtin_amdgcn_exp2f((x[i] - mx) * 1.44269504f);
            s += e; d += e * w[i];
        }
        d *= __builtin_amdgcn_rcpf(s);
        float ax, ay; anchor_xy(ncA, ax, ay);
        float axy = (side & 1) ? ay : ax;
        float v = (side < 2) ? (axy - d) : (axy + d);
        boxf[t] = v;                             // t == a*4+side
        if (nA < NN) pbb[((size_t)(b * NN + nA)) * 4 + side] = v;
    }

    // ---- sigmoid/softplus on the LDS-staged 64x80 score tile ----
    float sp = 0.f;
    #pragma unroll
    for (int k = 0; k < 5; k++) {
        int f = t + k * 256;
        int row = f / 20, c4 = f - row * 20;
        float vmask = (n0 + row < NN) ? 1.f : 0.f;
        float4 v4 = raw4[f];                     // ds_read_b128, conflict-free
        float xs[4] = {v4.x, v4.y, v4.z, v4.w};
        #pragma unroll
        for (int j = 0; j < 4; j++) {
            float x = xs[j];
            float e = __builtin_amdgcn_exp2f(-1.44269504f * fabsf(x));
            float r = __builtin_amdgcn_rcpf(1.0f + e);
            sp += vmask * (fmaxf(x, 0.f) + 0.69314718f * __builtin_amdgcn_logf(1.0f + e));
            int sl = cmap[c4 * 4 + j];
            if (sl < MM) sc[row * SLOTP + sl] = (x >= 0.f) ? r : e * r;
        }
    }
    __syncthreads();   // covers boxf + sc

    // ---- align: thread = (anchor t&63, gt-decade t>>6); 10 gts per thread ----
    const int nloc = t & 63;
    const int n    = n0 + nloc;
    const int mb   = (t >> 6) * 10;
    const int lane = t & 63;
    const bool valid = (n < NN);
    float cmax = -INFINITY;
    float4 p4 = ((const float4*)boxf)[nloc];
    const float px1 = p4.x, py1 = p4.y, px2 = p4.z, py2 = p4.w;
    const float a1 = (px2 - px1) * (py2 - py1);
    #pragma unroll
    for (int j = 0; j < 10; j++) {
        int m = mb + j;
        float gx1 = gtb[m*4+0], gy1 = gtb[m*4+1], gx2 = gtb[m*4+2], gy2 = gtb[m*4+3];
        float a2 = (gx2 - gx1) * (gy2 - gy1);
        float iw = fmaxf(fminf(px2, gx2) - fmaxf(px1, gx1), 0.f);
        float ih = fmaxf(fminf(py2, gy2) - fmaxf(py1, gy1), 0.f);
        float inter = iw * ih;
        float iou = fmaxf(inter * __builtin_amdgcn_rcpf(a1 + a2 - inter + 1e-16f), 0.f);
        float al = 0.f;
        if (valid) {
            float sg = sc[nloc * SLOTP + slotm[m]];
            float i2 = iou * iou;
            al = __builtin_amdgcn_sqrtf(sg) * (i2 * i2 * i2);
        }
        cmax = fmaxf(cmax, al);
        bool pos = valid && (al > 1e-9f);
        unsigned long long msk = __ballot(pos);
        if (msk) {
            int leader = __ffsll((long long)msk) - 1;
            int basev = 0;
            if (lane == leader) basev = atomicAdd(&cnts[b * MM + m], __popcll(msk));
            basev = __shfl(basev, leader);
            if (pos) {
                int ofs = __popcll(msk & ((1ull << lane) - 1ull));
                int idx = basev + ofs;
                if (idx < CAP)
                    lists[((size_t)(b * MM + m)) * CAP + idx] =
                        ((unsigned long long)__float_as_uint(al) << 32) | (unsigned)n;
            }
        }
    }
    cm[t] = cmax;
    __syncthreads();
    if (t < AB && valid)
        maxm[(size_t)b * NN + n] =
            fmaxf(fmaxf(cm[t], cm[t + 64]), fmaxf(cm[t + 128], cm[t + 192]));

    // softplus block reduction -> one atomic
    #pragma unroll
    for (int off = 32; off > 0; off >>= 1) sp += __shfl_down(sp, off);
    if ((t & 63) == 0) redf[t >> 6] = sp;
    __syncthreads();
    if (t == 0) atomicAdd(accum, redf[0] + redf[1] + redf[2] + redf[3]);
}

// ---------- K_topk: top-10 of compacted positives, LDS-only passes ----------
__global__ __launch_bounds__(64) void k_topk(const unsigned long long* __restrict__ lists,
                                             const int*   __restrict__ cnts,
                                             const float* __restrict__ maxm,
                                             int* __restrict__ tgt) {
    __shared__ unsigned long long keys[CAP];
    __shared__ unsigned long long sel[TOPKK];
    const int bm = blockIdx.x, b = bm / MM, m = bm % MM, t = threadIdx.x;
    int cnt = min(cnts[bm], CAP);
    int kk = min(TOPKK, cnt);
    for (int i = t; i < cnt; i += 64) {
        unsigned long long L = lists[(size_t)bm * CAP + i];
        keys[i] = (L & 0xFFFFFFFF00000000ull) | (0xFFFFFFFFull - (L & 0xFFFFFFFFull));
    }
    __syncthreads();
    for (int p = 0; p < kk; p++) {
        unsigned long long best = 0ull;
        for (int i = t; i < cnt; i += 64) best = keys[i] > best ? keys[i] : best;
        #pragma unroll
        for (int off = 32; off > 0; off >>= 1) {
            unsigned long long o = __shfl_xor(best, off);
            best = o > best ? o : best;
        }
        for (int i = t; i < cnt; i += 64) if (keys[i] == best) keys[i] = 0ull;
        if (t == 0) sel[p] = best;
        __syncthreads();
    }
    if (t < kk) {
        unsigned long long bb = sel[t];
        float v = __uint_as_float((unsigned)(bb >> 32));
        int n = (int)(0xFFFFFFFFull - (bb & 0xFFFFFFFFull));
        if (v == maxm[(size_t)b * NN + n]) atomicMin(&tgt[(size_t)b * NN + n], m);
    }
}

// ---------- K_fg: fg accumulation with block reduction ----------
__global__ __launch_bounds__(256) void k_fg(const int*   __restrict__ tgt,
                                            const int*   __restrict__ gl,
                                            const float* __restrict__ gb,
                                            const float* __restrict__ ps,
                                            const float* __restrict__ pbb,
                                            const float* __restrict__ maxm,
                                            float* __restrict__ accum) {
    int i = blockIdx.x * 256 + threadIdx.x;   // i in [0, B*N)
    int t = threadIdx.x;
    float vdot = 0.f, vbox = 0.f, vfg = 0.f;
    int tg = tgt[i];
    if (tg < MM) {
        int b = i / NN;
        int lab = gl[b * MM + tg];
        float x = ps[(size_t)i * NCC + lab];
        float mm = maxm[i];
        float4 p = *(const float4*)(pbb + (size_t)i * 4);
        const float* g = gb + ((size_t)b * MM + tg) * 4;
        float a1 = (p.z - p.x) * (p.w - p.y);
        float a2 = (g[2] - g[0]) * (g[3] - g[1]);
        float iw = fmaxf(fminf(p.z, g[2]) - fmaxf(p.x, g[0]), 0.f);
        float ih = fmaxf(fminf(p.w, g[3]) - fmaxf(p.y, g[1]), 0.f);
        float inter = iw * ih;
        float iou = inter / (a1 + a2 - inter + 1e-16f);
        vdot = x * mm; vbox = 1.0f - iou; vfg = 1.0f;
    }
    #pragma unroll
    for (int off = 32; off > 0; off >>= 1) {
        vdot += __shfl_down(vdot, off);
        vbox += __shfl_down(vbox, off);
        vfg  += __shfl_down(vfg,  off);
    }
    __shared__ float r[3][4];
    if ((t & 63) == 0) { int wv = t >> 6; r[0][wv] = vdot; r[1][wv] = vbox; r[2][wv] = vfg; }
    __syncthreads();
    if (t < 3) {
        float s = r[t][0] + r[t][1] + r[t][2] + r[t][3];
        if (s != 0.f) atomicAdd(&accum[1 + t], s);
    }
}

// ---------- K_final ----------
__global__ void k_final(const float* __restrict__ accum, float* __restrict__ out) {
    float S0 = accum[0], dot = accum[1], box = accum[2], fg = accum[3];
    float ts = fmaxf(fg, 1.0f);
    float cls = (S0 - dot) / ts;
    float lb = (fg > 0.f) ? box / fg : 0.f;
    out[0] = cls + 1.5f * lb;
}

// ---------- launch ----------
extern "C" void kernel_launch(void* const* d_in, const int* in_sizes, int n_in,
                              void* d_out, int out_size, void* d_ws, size_t ws_size,
                              hipStream_t stream) {
    const float* ps = (const float*)d_in[0];   // pred_scores (B,N,NC)
    const float* pd = (const float*)d_in[1];   // pred_dist   (B,N,64)
    const int*   gl = (const int*)  d_in[2];   // gt_labels   (B,M,1)
    const float* gb = (const float*)d_in[3];   // gt_bboxes   (B,M,4)
    const float* w  = (const float*)d_in[4];   // dfl_weight  (16)

    char* ws = (char*)d_ws;
    constexpr size_t ACC_BYTES  = 256;                                      // accum floats + pad
    constexpr size_t CNT_BYTES  = 8192;                                     // 1280 ints, padded
    constexpr size_t PBB_BYTES  = (size_t)BB * NN * 4 * sizeof(float);      // 4.30 MB
    constexpr size_t MAXM_BYTES = (size_t)BB * NN * sizeof(float);          // 1.08 MB
    constexpr size_t TGT_BYTES  = (size_t)BB * NN * sizeof(int);            // 1.08 MB

    float* accum = (float*)ws;
    int*   cnts  = (int*)  (ws + ACC_BYTES);
    float* pbb   = (float*)(ws + ACC_BYTES + CNT_BYTES);
    float* maxm  = (float*)(ws + ACC_BYTES + CNT_BYTES + PBB_BYTES);
    int*   tgt   = (int*)  (ws + ACC_BYTES + CNT_BYTES + PBB_BYTES + MAXM_BYTES);
    unsigned long long* lists =
        (unsigned long long*)(ws + ACC_BYTES + CNT_BYTES + PBB_BYTES + MAXM_BYTES + TGT_BYTES);

    // single small memset: accum + cnts contiguous (tgt init fused into k_mono)
    hipMemsetAsync(ws, 0, ACC_BYTES + CNT_BYTES, stream);

    dim3 gmono((NN + AB - 1) / AB, BB);
    k_mono<<<gmono, 256, 0, stream>>>(ps, pd, gl, gb, w, pbb, maxm, cnts, lists, accum, tgt);
    k_topk<<<BB * MM, 64, 0, stream>>>(lists, cnts, maxm, tgt);
    k_fg<<<BB * NN / 256, 256, 0, stream>>>(tgt, gl, gb, ps, pbb, maxm, accum);
    k_final<<<1, 1, 0, stream>>>(accum, (float*)d_out);
}

// Round 10
// 204.978 us; speedup vs baseline: 1.0140x; 1.0140x over previous
//
#include <hip/hip_runtime.h>
#include <cstdint>
#include <cstddef>

#define BB 32
#define NN 8400
#define NCC 80
#define MM 40
#define RM 16
#define TOPKK 10
#define CAP 2048      // max positives per (b,m); measured worst case ~450, 4.5x margin
#define SLOTP 41      // LDS stride for per-slot sigmoid tile; gcd(41,32)=1
#define AB 64         // anchors per block (16 per wave)

// ---------- helpers ----------
__device__ __forceinline__ void anchor_xy(int n, float& ax, float& ay) {
    int s, x, y;
    if (n < 6400)      { s = 8;  y = n / 80;            x = n - y * 80; }
    else if (n < 8000) { int i = n - 6400; s = 16; y = i / 40; x = i - y * 40; }
    else               { int i = n - 8000; s = 32; y = i / 20; x = i - y * 20; }
    ax = ((float)x + 0.5f) * (float)s;
    ay = ((float)y + 0.5f) * (float)s;
}

// ---------- K_mono: DFL + sigmoid/softplus + align with WAVE-PRIVATE sub-tiles ----------
// grid: (ceil(N/64), B), 256 threads = 4 waves; wave w owns anchors [16w,16w+16).
// The heavy path (ps loads -> sigmoid/softplus -> align) is BARRIER-FREE per wave:
// phase1->phase2 handoff uses s_waitcnt lgkmcnt(0)+sched_barrier (wave-synchronous
// LDS), not s_barrier. Block barriers only in setup (cmap dedup) + final reduce.
// Rationale: R1-R9 all plateaued at 71-81us with VALUBusy ~31% regardless of
// occupancy/LDS/VGPR — the invariant was block-wide barrier coupling per phase.
__global__ __launch_bounds__(256) void k_mono(const float* __restrict__ ps,
                                              const float* __restrict__ pd,
                                              const int*   __restrict__ gl,
                                              const float* __restrict__ gb,
                                              const float* __restrict__ w,
                                              float* __restrict__ pbb,
                                              float* __restrict__ maxm,
                                              int*   __restrict__ cnts,
                                              unsigned long long* __restrict__ lists,
                                              float* __restrict__ accum,
                                              int*   __restrict__ tgt) {
    __shared__ float sc[4 * 16 * SLOTP];   // wave-private 16xSLOTP sigmoid tiles, 10.5 KB
    __shared__ float boxf[AB * 4];         // pred boxes; t = anchor*4+side maps 1:1
    __shared__ float gtb[MM * 4];
    __shared__ int   glab[MM];
    __shared__ int   slotm[MM];
    __shared__ int   cmap[NCC];
    __shared__ float redf[4];
    const int b  = blockIdx.y;
    const int n0 = blockIdx.x * AB;
    const int t  = threadIdx.x;
    const int wv = t >> 6;                 // wave index 0..3
    const int l  = t & 63;                 // lane

    // fused tgt init (replaces a 1 MB memset node)
    if (t < AB && n0 + t < NN) tgt[(size_t)b * NN + n0 + t] = 0x7F7F7F7F;

    // ---- setup: gt data + label dedup (2 cheap block barriers, before heavy path) ----
    if (t < MM * 4)              gtb[t] = gb[b * MM * 4 + t];
    if (t >= 192 && t < 192+MM)  glab[t - 192] = gl[b * MM + (t - 192)];
    if (t >= 96 && t < 96+NCC)   cmap[t - 96] = 0x7FFFFFFF;
    __syncthreads();
    if (t < MM) atomicMin(&cmap[glab[t]], t);   // parallel label dedup
    __syncthreads();
    if (t < MM) slotm[t] = cmap[glab[t]];       // slot = representative m, in [0,MM)
    __syncthreads();                            // slotm visible to all waves

    // =================== barrier-free per-wave heavy path ===================

    // ---- pd loads: 1 (anchor,side) per thread; anchor t>>2 belongs to wave t>>6 ----
    const int aT   = t >> 2, side = t & 3;      // anchor-in-block, box side
    const int nA   = n0 + aT;
    const int ncA  = min(nA, NN - 1);
    const float* p = pd + (((size_t)(b * NN + ncA)) * 4 + side) * RM;
    float4 xa0 = *(const float4*)(p);
    float4 xa1 = *(const float4*)(p + 4);
    float4 xa2 = *(const float4*)(p + 8);
    float4 xa3 = *(const float4*)(p + 12);

    // ---- ps loads: wave-private 16x80 tile, 5 float4 per lane ----
    float4 vv[5];
    #pragma unroll
    for (int k = 0; k < 5; k++) {
        int fl = l + k * 64;                    // [0,320): wave-local float4 index
        int rl = fl / 20, c4 = fl - rl * 20;    // row-in-wave-tile, float4-column
        int nc = min(n0 + wv * 16 + rl, NN - 1);
        vv[k] = *(const float4*)(ps + ((size_t)(b * NN + nc)) * NCC + c4 * 4);
    }

    // ---- DFL softmax-dot -> one box component per thread ----
    {
        float x[RM];
        x[0]=xa0.x;  x[1]=xa0.y;  x[2]=xa0.z;  x[3]=xa0.w;
        x[4]=xa1.x;  x[5]=xa1.y;  x[6]=xa1.z;  x[7]=xa1.w;
        x[8]=xa2.x;  x[9]=xa2.y;  x[10]=xa2.z; x[11]=xa2.w;
        x[12]=xa3.x; x[13]=xa3.y; x[14]=xa3.z; x[15]=xa3.w;
        float mx = x[0];
        #pragma unroll
        for (int i = 1; i < RM; i++) mx = fmaxf(mx, x[i]);
        float s = 0.f, d = 0.f;
        #pragma unroll
        for (int i = 0; i < RM; i++) {
            float e = __builtin_amdgcn_exp2f((x[i] - mx) * 1.44269504f);
            s += e; d += e * w[i];
        }
        d *= __builtin_amdgcn_rcpf(s);
        float ax, ay; anchor_xy(ncA, ax, ay);
        float axy = (side & 1) ? ay : ax;
        float v = (side < 2) ? (axy - d) : (axy + d);
        boxf[t] = v;                            // anchor aT, comp side (wave-local rows)
        if (nA < NN) pbb[((size_t)(b * NN + nA)) * 4 + side] = v;
    }

    // ---- phase 1: sigmoid/softplus on the wave's 16x80 tile ----
    float sp = 0.f;
    #pragma unroll
    for (int k = 0; k < 5; k++) {
        int fl = l + k * 64;
        int rl = fl / 20, c4 = fl - rl * 20;
        float vmask = (n0 + wv * 16 + rl < NN) ? 1.f : 0.f;
        float xs[4] = {vv[k].x, vv[k].y, vv[k].z, vv[k].w};
        #pragma unroll
        for (int j = 0; j < 4; j++) {
            float x = xs[j];
            float e = __builtin_amdgcn_exp2f(-1.44269504f * fabsf(x));
            float r = __builtin_amdgcn_rcpf(1.0f + e);
            sp += vmask * (fmaxf(x, 0.f) + 0.69314718f * __builtin_amdgcn_logf(1.0f + e));
            int sl = cmap[c4 * 4 + j];
            if (sl < MM) sc[(wv * 16 + rl) * SLOTP + sl] = (x >= 0.f) ? r : e * r;
        }
    }

    // ---- wave-synchronous fence: sc + boxf written by this wave's lanes ----
    asm volatile("s_waitcnt lgkmcnt(0)" ::: "memory");
    __builtin_amdgcn_sched_barrier(0);          // rule 18: block compiler hoisting

    // ---- phase 2: lane = (anchor l&15, gt-group l>>4); 10 gts per lane ----
    const int aL = l & 15;
    const int g  = l >> 4;
    const int n  = n0 + wv * 16 + aL;
    const bool valid = (n < NN);
    float cmax = -INFINITY;
    float4 p4 = ((const float4*)boxf)[wv * 16 + aL];
    const float px1 = p4.x, py1 = p4.y, px2 = p4.z, py2 = p4.w;
    const float a1 = (px2 - px1) * (py2 - py1);
    #pragma unroll
    for (int j = 0; j < 10; j++) {
        int m = g * 10 + j;                     // 16 lanes share m -> LDS broadcast
        float gx1 = gtb[m*4+0], gy1 = gtb[m*4+1], gx2 = gtb[m*4+2], gy2 = gtb[m*4+3];
        float a2 = (gx2 - gx1) * (gy2 - gy1);
        float iw = fmaxf(fminf(px2, gx2) - fmaxf(px1, gx1), 0.f);
        float ih = fmaxf(fminf(py2, gy2) - fmaxf(py1, gy1), 0.f);
        float inter = iw * ih;
        float iou = fmaxf(inter * __builtin_amdgcn_rcpf(a1 + a2 - inter + 1e-16f), 0.f);
        float al = 0.f;
        if (valid) {
            float sg = sc[(wv * 16 + aL) * SLOTP + slotm[m]];
            float i2 = iou * iou;
            al = __builtin_amdgcn_sqrtf(sg) * (i2 * i2 * i2);
        }
        cmax = fmaxf(cmax, al);
        if (al > 1e-9f) {                       // per-lane push; positives are rare
            int idx = atomicAdd(&cnts[b * MM + m], 1);
            if (idx < CAP)
                lists[((size_t)(b * MM + m)) * CAP + idx] =
                    ((unsigned long long)__float_as_uint(al) << 32) | (unsigned)n;
        }
    }
    // reduce cmax over the 4 gt-groups of each anchor (lanes l, l^16, l^32, l^48)
    cmax = fmaxf(cmax, __shfl_xor(cmax, 16));
    cmax = fmaxf(cmax, __shfl_xor(cmax, 32));
    if (l < 16 && valid) maxm[(size_t)b * NN + n] = cmax;

    // =================== end barrier-free path ===================

    // softplus block reduction -> one atomic
    #pragma unroll
    for (int off = 32; off > 0; off >>= 1) sp += __shfl_down(sp, off);
    if (l == 0) redf[wv] = sp;
    __syncthreads();
    if (t == 0) atomicAdd(accum, redf[0] + redf[1] + redf[2] + redf[3]);
}

// ---------- K_topk: top-10 of compacted positives, LDS-only passes ----------
__global__ __launch_bounds__(64) void k_topk(const unsigned long long* __restrict__ lists,
                                             const int*   __restrict__ cnts,
                                             const float* __restrict__ maxm,
                                             int* __restrict__ tgt) {
    __shared__ unsigned long long keys[CAP];
    __shared__ unsigned long long sel[TOPKK];
    const int bm = blockIdx.x, b = bm / MM, m = bm % MM, t = threadIdx.x;
    int cnt = min(cnts[bm], CAP);
    int kk = min(TOPKK, cnt);
    for (int i = t; i < cnt; i += 64) {
        unsigned long long L = lists[(size_t)bm * CAP + i];
        keys[i] = (L & 0xFFFFFFFF00000000ull) | (0xFFFFFFFFull - (L & 0xFFFFFFFFull));
    }
    __syncthreads();
    for (int p = 0; p < kk; p++) {
        unsigned long long best = 0ull;
        for (int i = t; i < cnt; i += 64) best = keys[i] > best ? keys[i] : best;
        #pragma unroll
        for (int off = 32; off > 0; off >>= 1) {
            unsigned long long o = __shfl_xor(best, off);
            best = o > best ? o : best;
        }
        for (int i = t; i < cnt; i += 64) if (keys[i] == best) keys[i] = 0ull;
        if (t == 0) sel[p] = best;
        __syncthreads();
    }
    if (t < kk) {
        unsigned long long bb = sel[t];
        float v = __uint_as_float((unsigned)(bb >> 32));
        int n = (int)(0xFFFFFFFFull - (bb & 0xFFFFFFFFull));
        if (v == maxm[(size_t)b * NN + n]) atomicMin(&tgt[(size_t)b * NN + n], m);
    }
}

// ---------- K_fg: fg accumulation with block reduction ----------
__global__ __launch_bounds__(256) void k_fg(const int*   __restrict__ tgt,
                                            const int*   __restrict__ gl,
                                            const float* __restrict__ gb,
                                            const float* __restrict__ ps,
                                            const float* __restrict__ pbb,
                                            const float* __restrict__ maxm,
                                            float* __restrict__ accum) {
    int i = blockIdx.x * 256 + threadIdx.x;   // i in [0, B*N)
    int t = threadIdx.x;
    float vdot = 0.f, vbox = 0.f, vfg = 0.f;
    int tg = tgt[i];
    if (tg < MM) {
        int b = i / NN;
        int lab = gl[b * MM + tg];
        float x = ps[(size_t)i * NCC + lab];
        float mm = maxm[i];
        float4 p = *(const float4*)(pbb + (size_t)i * 4);
        const float* g = gb + ((size_t)b * MM + tg) * 4;
        float a1 = (p.z - p.x) * (p.w - p.y);
        float a2 = (g[2] - g[0]) * (g[3] - g[1]);
        float iw = fmaxf(fminf(p.z, g[2]) - fmaxf(p.x, g[0]), 0.f);
        float ih = fmaxf(fminf(p.w, g[3]) - fmaxf(p.y, g[1]), 0.f);
        float inter = iw * ih;
        float iou = inter / (a1 + a2 - inter + 1e-16f);
        vdot = x * mm; vbox = 1.0f - iou; vfg = 1.0f;
    }
    #pragma unroll
    for (int off = 32; off > 0; off >>= 1) {
        vdot += __shfl_down(vdot, off);
        vbox += __shfl_down(vbox, off);
        vfg  += __shfl_down(vfg,  off);
    }
    __shared__ float r[3][4];
    if ((t & 63) == 0) { int wv = t >> 6; r[0][wv] = vdot; r[1][wv] = vbox; r[2][wv] = vfg; }
    __syncthreads();
    if (t < 3) {
        float s = r[t][0] + r[t][1] + r[t][2] + r[t][3];
        if (s != 0.f) atomicAdd(&accum[1 + t], s);
    }
}

// ---------- K_final ----------
__global__ void k_final(const float* __restrict__ accum, float* __restrict__ out) {
    float S0 = accum[0], dot = accum[1], box = accum[2], fg = accum[3];
    float ts = fmaxf(fg, 1.0f);
    float cls = (S0 - dot) / ts;
    float lb = (fg > 0.f) ? box / fg : 0.f;
    out[0] = cls + 1.5f * lb;
}

// ---------- launch ----------
extern "C" void kernel_launch(void* const* d_in, const int* in_sizes, int n_in,
                              void* d_out, int out_size, void* d_ws, size_t ws_size,
                              hipStream_t stream) {
    const float* ps = (const float*)d_in[0];   // pred_scores (B,N,NC)
    const float* pd = (const float*)d_in[1];   // pred_dist   (B,N,64)
    const int*   gl = (const int*)  d_in[2];   // gt_labels   (B,M,1)
    const float* gb = (const float*)d_in[3];   // gt_bboxes   (B,M,4)
    const float* w  = (const float*)d_in[4];   // dfl_weight  (16)

    char* ws = (char*)d_ws;
    constexpr size_t ACC_BYTES  = 256;                                      // accum floats + pad
    constexpr size_t CNT_BYTES  = 8192;                                     // 1280 ints, padded
    constexpr size_t PBB_BYTES  = (size_t)BB * NN * 4 * sizeof(float);      // 4.30 MB
    constexpr size_t MAXM_BYTES = (size_t)BB * NN * sizeof(float);          // 1.08 MB
    constexpr size_t TGT_BYTES  = (size_t)BB * NN * sizeof(int);            // 1.08 MB

    float* accum = (float*)ws;
    int*   cnts  = (int*)  (ws + ACC_BYTES);
    float* pbb   = (float*)(ws + ACC_BYTES + CNT_BYTES);
    float* maxm  = (float*)(ws + ACC_BYTES + CNT_BYTES + PBB_BYTES);
    int*   tgt   = (int*)  (ws + ACC_BYTES + CNT_BYTES + PBB_BYTES + MAXM_BYTES);
    unsigned long long* lists =
        (unsigned long long*)(ws + ACC_BYTES + CNT_BYTES + PBB_BYTES + MAXM_BYTES + TGT_BYTES);

    // single small memset: accum + cnts contiguous (tgt init fused into k_mono)
    hipMemsetAsync(ws, 0, ACC_BYTES + CNT_BYTES, stream);

    dim3 gmono((NN + AB - 1) / AB, BB);
    k_mono<<<gmono, 256, 0, stream>>>(ps, pd, gl, gb, w, pbb, maxm, cnts, lists, accum, tgt);
    k_topk<<<BB * MM, 64, 0, stream>>>(lists, cnts, maxm, tgt);
    k_fg<<<BB * NN / 256, 256, 0, stream>>>(tgt, gl, gb, ps, pbb, maxm, accum);
    k_final<<<1, 1, 0, stream>>>(accum, (float*)d_out);
}